// Round 7
// baseline (158.402 us; speedup 1.0000x reference)
//
#include <hip/hip_runtime.h>
#include <math.h>

// Problem constants (from reference)
#define BB   4
#define NN   40
#define TT   64
#define NIN  4
#define NEMB 32
#define NHID 64
#define EPSW 1e-5f

__device__ __forceinline__ float fast_sigmoid(float x) {
    return __fdividef(1.0f, 1.0f + __expf(-x));
}
__device__ __forceinline__ float fast_tanh(float x) {
    return __fdividef(2.0f, 1.0f + __expf(-2.0f * x)) - 1.0f;
}
// broadcast lane l's value of v across the wave (uniform l -> v_readlane)
__device__ __forceinline__ float lanebcast(float v, int l) {
    return __int_as_float(__builtin_amdgcn_readlane(__float_as_int(v), l));
}

// ---------------------------------------------------------------------------
// Kernel 1: per-(b,n) LSTM chain + temporal attention pool (output cols 0..63)
// Grid: 160 blocks (b*40+n), 64 threads = ONE WAVE per chain.
//
// Counter-driven history:
//  * R2: full unroll -> I-cache thrash. Step loop stays ROLLED.
//  * R3-R6: with the "wave = gate type" split (4 waves/chain), three
//    different dot-product implementations all landed at ~1550-1700
//    cyc/step while VALU issue is only ~400 -> the ~1100 cyc/step blob is
//    the cross-wave act exchange (ds_write -> waitcnt -> s_barrier across
//    4 SIMDs -> ds_read ~120cyc -> dependent act), unhideable at
//    1 wave/SIMD. Structural; stop tweaking the dot.
//  * R7 (this): BARRIER-FREE. Lane j owns unit j and computes ALL FOUR
//    gates (4 W_hh rows = 256 weights/lane; gfx950 unified 512-reg file,
//    worst case L1 reloads). h stays register-distributed; readlane
//    broadcasts (imm lane). Zero LDS / zero barriers in the loop ->
//    step cost = pure issue (~650-700 cyc).
// ---------------------------------------------------------------------------
__global__ __launch_bounds__(64, 1)
void k_lstm(const float* __restrict__ inputs,
            const float* __restrict__ W_emb,
            const float* __restrict__ b_emb,
            const float* __restrict__ W_ih,
            const float* __restrict__ W_hh,
            const float* __restrict__ b_ih,
            const float* __restrict__ b_hh,
            const float* __restrict__ W_att,
            float* __restrict__ out,
            float* __restrict__ hs_g)
{
    __shared__ __align__(16) float s_hs[TT * (NHID + 1)];  // h history, pad 65
    __shared__ __align__(16) float s_war[NHID];            // W_att[0,64:128]
    __shared__ __align__(16) float s_p[TT];                // softmax weights

    const int m = blockIdx.x;        // b*NN + n
    const int j = threadIdx.x;       // hidden unit / lane, 0..63

    s_war[j] = W_att[NHID + j];

    // lane t holds x[t] (float4) in registers
    const float4 xl = ((const float4*)(inputs + m * (TT * NIN)))[j];

    // ---- fold embedding into the 4 gate rows of THIS unit:
    //      wcX[4] = row(gX) of W_ih @ W_emb,  bcX = b_ih+b_hh+row(gX).b_emb
    #define FOLD(PFX, ROW)                                                   \
        float PFX##0 = 0.f, PFX##1 = 0.f, PFX##2 = 0.f, PFX##3 = 0.f;        \
        float PFX##b = b_ih[ROW] + b_hh[ROW];                                \
        {                                                                    \
            const float4* wih4 = (const float4*)(W_ih + (ROW) * NEMB);       \
            _Pragma("unroll")                                                \
            for (int e4 = 0; e4 < NEMB / 4; ++e4) {                          \
                float4 wv = wih4[e4];                                        \
                const float4* wm = ((const float4*)W_emb) + 4 * e4;          \
                PFX##0 += wv.x*wm[0].x + wv.y*wm[1].x + wv.z*wm[2].x + wv.w*wm[3].x; \
                PFX##1 += wv.x*wm[0].y + wv.y*wm[1].y + wv.z*wm[2].y + wv.w*wm[3].y; \
                PFX##2 += wv.x*wm[0].z + wv.y*wm[1].z + wv.z*wm[2].z + wv.w*wm[3].z; \
                PFX##3 += wv.x*wm[0].w + wv.y*wm[1].w + wv.z*wm[2].w + wv.w*wm[3].w; \
                PFX##b += wv.x*b_emb[4*e4+0] + wv.y*b_emb[4*e4+1]            \
                        + wv.z*b_emb[4*e4+2] + wv.w*b_emb[4*e4+3];           \
            }                                                                \
        }
    FOLD(wcI, j)
    FOLD(wcF, NHID + j)
    FOLD(wcG, 2 * NHID + j)
    FOLD(wcO, 3 * NHID + j)
    #undef FOLD

    // ---- W_hh rows for the 4 gates of unit j (64 floats each) ----
    float4 wI[16], wF[16], wG[16], wO[16];
    {
        const float4* pI = (const float4*)(W_hh + (size_t)(j) * NHID);
        const float4* pF = (const float4*)(W_hh + (size_t)(NHID + j) * NHID);
        const float4* pG = (const float4*)(W_hh + (size_t)(2 * NHID + j) * NHID);
        const float4* pO = (const float4*)(W_hh + (size_t)(3 * NHID + j) * NHID);
        #pragma unroll
        for (int k = 0; k < 16; ++k) {
            wI[k] = pI[k]; wF[k] = pF[k]; wG[k] = pG[k]; wO[k] = pO[k];
        }
    }

    // ---- recurrence: 64 steps, NO barriers, NO LDS on the critical path ----
    float c = 0.0f, h = 0.0f;
    #pragma unroll 1
    for (int t = 0; t < TT; ++t) {
        // x-term: 4 uniform readlanes (lane t holds x[t])
        const float xb0 = lanebcast(xl.x, t);
        const float xb1 = lanebcast(xl.y, t);
        const float xb2 = lanebcast(xl.z, t);
        const float xb3 = lanebcast(xl.w, t);

        // two accumulators per gate (dep chain 32*4cyc < issue; 8 regs)
        float aI0 = wcIb + xb0 * wcI0 + xb2 * wcI2;
        float aI1 = xb1 * wcI1 + xb3 * wcI3;
        float aF0 = wcFb + xb0 * wcF0 + xb2 * wcF2;
        float aF1 = xb1 * wcF1 + xb3 * wcF3;
        float aG0 = wcGb + xb0 * wcG0 + xb2 * wcG2;
        float aG1 = xb1 * wcG1 + xb3 * wcG3;
        float aO0 = wcOb + xb0 * wcO0 + xb2 * wcO2;
        float aO1 = xb1 * wcO1 + xb3 * wcO3;

        // h . W_hh for all 4 gates: 64 readlane (imm lane) + 256 fmac
        #pragma unroll
        for (int k = 0; k < 16; ++k) {
            const float h0 = lanebcast(h, 4 * k + 0);
            const float h1 = lanebcast(h, 4 * k + 1);
            const float h2 = lanebcast(h, 4 * k + 2);
            const float h3 = lanebcast(h, 4 * k + 3);
            aI0 += h0 * wI[k].x; aI1 += h1 * wI[k].y;
            aI0 += h2 * wI[k].z; aI1 += h3 * wI[k].w;
            aF0 += h0 * wF[k].x; aF1 += h1 * wF[k].y;
            aF0 += h2 * wF[k].z; aF1 += h3 * wF[k].w;
            aG0 += h0 * wG[k].x; aG1 += h1 * wG[k].y;
            aG0 += h2 * wG[k].z; aG1 += h3 * wG[k].w;
            aO0 += h0 * wO[k].x; aO1 += h1 * wO[k].y;
            aO0 += h2 * wO[k].z; aO1 += h3 * wO[k].w;
        }

        const float ig = fast_sigmoid(aI0 + aI1);
        const float fg = fast_sigmoid(aF0 + aF1);
        const float gg = fast_tanh(aG0 + aG1);
        const float og = fast_sigmoid(aO0 + aO1);
        c = fg * c + ig * gg;
        h = og * fast_tanh(c);
        s_hs[t * (NHID + 1) + j] = h;   // off critical path; no wait in-loop
    }
    __syncthreads();   // single wave: cheap; orders s_hs for epilogue

    // ---- dump hs to global for kernel 2 (coalesced 256B stores) ----
    #pragma unroll 1
    for (int t = 0; t < TT; ++t)
        hs_g[m * (TT * NHID) + t * NHID + j] = s_hs[t * (NHID + 1) + j];

    // ---- temporal attention pooling (softmax over t, i-independent) ----
    {
        const int t = j;   // lane = time index
        float r = 0.0f;
        #pragma unroll
        for (int k = 0; k < NHID; ++k)
            r += s_hs[t * (NHID + 1) + k] * s_war[k];
        float mx = r;
        #pragma unroll
        for (int off = 32; off >= 1; off >>= 1)
            mx = fmaxf(mx, __shfl_xor(mx, off));
        const float e = __expf(r - mx);
        float s = e;
        #pragma unroll
        for (int off = 32; off >= 1; off >>= 1)
            s += __shfl_xor(s, off);
        s_p[t] = __fdividef(e, s);
    }
    __syncthreads();

    {
        float acc = 0.0f;
        #pragma unroll
        for (int t = 0; t < TT; ++t)
            acc += s_p[t] * s_hs[t * (NHID + 1) + j];
        out[m * (2 * NHID) + j] = fast_tanh(acc);
    }
}

// ---------------------------------------------------------------------------
// Kernel 2: spatial inverse-distance aggregation (output cols 64..127)
// chsum[b,i,h] = sum_t sum_{j!=i} hs[b,j,t,h] / (dist(i,j,t)+eps)
// Grid: 160 blocks (b*40+i), 256 threads = (t-quarter q, h).
// ---------------------------------------------------------------------------
__global__ __launch_bounds__(256)
void k_spatial(const float* __restrict__ inputs,
               const float* __restrict__ hs_g,
               float* __restrict__ out)
{
    __shared__ float s_w[TT * NN];          // 2560 inverse-distance weights
    __shared__ float s_part[4 * NHID];

    const int bi  = blockIdx.x;
    const int b   = bi / NN;
    const int i   = bi - b * NN;
    const int tid = threadIdx.x;

    for (int idx = tid; idx < TT * NN; idx += 256) {
        const int t = idx / NN;
        const int j = idx - t * NN;
        const float* pi = inputs + ((b * NN + i) * TT + t) * NIN;
        const float* pj = inputs + ((b * NN + j) * TT + t) * NIN;
        const float dx = pi[0] - pj[0];
        const float dy = pi[1] - pj[1];
        const float d  = sqrtf(dx * dx + dy * dy);
        s_w[idx] = (j == i) ? 0.0f : __fdividef(1.0f, d + EPSW);
    }
    __syncthreads();

    const int h = tid & 63;
    const int q = tid >> 6;          // t-quarter

    const float* base = hs_g + (size_t)b * NN * TT * NHID + h;
    float a0 = 0.f, a1 = 0.f, a2 = 0.f, a3 = 0.f;
    for (int t = q * 16; t < q * 16 + 16; ++t) {
        const float* hp = base + t * NHID;
        const float* wp = s_w + t * NN;
        #pragma unroll
        for (int j = 0; j < NN; j += 4) {
            a0 += wp[j + 0] * hp[(size_t)(j + 0) * TT * NHID];
            a1 += wp[j + 1] * hp[(size_t)(j + 1) * TT * NHID];
            a2 += wp[j + 2] * hp[(size_t)(j + 2) * TT * NHID];
            a3 += wp[j + 3] * hp[(size_t)(j + 3) * TT * NHID];
        }
    }
    s_part[q * NHID + h] = (a0 + a1) + (a2 + a3);
    __syncthreads();

    if (tid < NHID) {
        const float s = s_part[tid] + s_part[NHID + tid] +
                        s_part[2 * NHID + tid] + s_part[3 * NHID + tid];
        out[bi * (2 * NHID) + NHID + tid] = fast_tanh(s);
    }
}

extern "C" void kernel_launch(void* const* d_in, const int* in_sizes, int n_in,
                              void* d_out, int out_size, void* d_ws, size_t ws_size,
                              hipStream_t stream) {
    const float* inputs = (const float*)d_in[0];
    // d_in[1..4]: rel_rec / rel_send / rel_rec_t / rel_send_t (one-hot, folded)
    const float* W_emb  = (const float*)d_in[5];
    const float* b_emb  = (const float*)d_in[6];
    const float* W_ih   = (const float*)d_in[7];
    const float* W_hh   = (const float*)d_in[8];
    const float* b_ih   = (const float*)d_in[9];
    const float* b_hh   = (const float*)d_in[10];
    const float* W_att  = (const float*)d_in[11];
    // d_in[12] = b_att: cancels in the softmax, unused.

    float* outp = (float*)d_out;
    float* hs_g = (float*)d_ws;   // 160*64*64 floats = 2.62 MB

    hipLaunchKernelGGL(k_lstm, dim3(BB * NN), dim3(64), 0, stream,
                       inputs, W_emb, b_emb, W_ih, W_hh, b_ih, b_hh, W_att,
                       outp, hs_g);
    hipLaunchKernelGGL(k_spatial, dim3(BB * NN), dim3(256), 0, stream,
                       inputs, hs_g, outp);
}

// Round 10
// 156.597 us; speedup vs baseline: 1.0115x; 1.0115x over previous
//
#include <hip/hip_runtime.h>
#include <math.h>

// Problem constants (from reference)
#define BB   4
#define NN   40
#define TT   64
#define NIN  4
#define NEMB 32
#define NHID 64
#define EPSW 1e-5f

// NOTE: must be __fp16 (not _Float16) for the amdgcn builtins (R8 fail).
typedef __fp16 half2v __attribute__((ext_vector_type(2)));

__device__ __forceinline__ float fast_sigmoid(float x) {
    return __fdividef(1.0f, 1.0f + __expf(-x));
}
__device__ __forceinline__ float fast_tanh(float x) {
    return __fdividef(2.0f, 1.0f + __expf(-2.0f * x)) - 1.0f;
}
__device__ __forceinline__ float lanebcast(float v, int l) {
    return __int_as_float(__builtin_amdgcn_readlane(__float_as_int(v), l));
}
__device__ __forceinline__ half2v i2h2(int v) {
    union { int i; half2v h; } u; u.i = v; return u.h;
}
__device__ __forceinline__ int h22i(half2v v) {
    union { int i; half2v h; } u; u.h = v; return u.i;
}
// RNE pack (v_cvt_f16_f32 rounds nearest-even; cvt_pkrtz is RTZ -> biased,
// caused R9's 3.3e-2 linear error accumulation over the 64-step recurrence)
__device__ __forceinline__ half2v pack_rne(float a, float b) {
    half2v r; r.x = (__fp16)a; r.y = (__fp16)b; return r;
}

// ---------------------------------------------------------------------------
// Kernel 1: per-(b,n) LSTM chain + temporal attention pool (output cols 0..63)
// Grid: 160 blocks (b*40+n), 64 threads = ONE WAVE per chain.
//
// Counter-driven history:
//  * R2: full unroll of t-loop -> I-cache thrash. t-loop stays ROLLED.
//  * R3-R7: any variant whose weights don't fit in registers is L1-BW-bound
//    on per-step weight re-fetch (VGPR 44-152, FETCH inflation, 1600-2500
//    cyc/step). f16-packed single-wave is the only resident layout.
//  * R9: structure worked, numerics failed (3.3e-2 > 2e-2): cvt_pkrtz is
//    ROUND-TOWARD-ZERO -> biased error -> linear compounding over 64 steps.
//  * R10 (this): RNE packing everywhere + h fed into the dot as hi+residual
//    (h16 + e16, ~21 effective bits; same weight regs reused, +128 dot2).
//    Remaining error = RNE f16 weight quantization, random-walk -> ~1e-3.
// ---------------------------------------------------------------------------
__global__ __launch_bounds__(64, 1)
void k_lstm(const float* __restrict__ inputs,
            const float* __restrict__ W_emb,
            const float* __restrict__ b_emb,
            const float* __restrict__ W_ih,
            const float* __restrict__ W_hh,
            const float* __restrict__ b_ih,
            const float* __restrict__ b_hh,
            const float* __restrict__ W_att,
            float* __restrict__ out,
            float* __restrict__ hs_g)
{
    __shared__ __align__(16) float s_hs[TT * (NHID + 1)];  // h history, pad 65
    __shared__ __align__(16) float s_war[NHID];            // W_att[0,64:128]
    __shared__ __align__(16) float s_p[TT];                // softmax weights

    const int m = blockIdx.x;        // b*NN + n
    const int j = threadIdx.x;       // hidden unit / lane, 0..63

    s_war[j] = W_att[NHID + j];

    // lane t holds x[t] (float4) in registers
    const float4 xl = ((const float4*)(inputs + m * (TT * NIN)))[j];

    // ---- fold embedding into the 4 gate rows of THIS unit (fp32):
    //      wcX[4] = row(gX) of W_ih @ W_emb,  bcX = b_ih+b_hh+row(gX).b_emb
    #define FOLD(PFX, ROW)                                                   \
        float PFX##0 = 0.f, PFX##1 = 0.f, PFX##2 = 0.f, PFX##3 = 0.f;        \
        float PFX##b = b_ih[ROW] + b_hh[ROW];                                \
        {                                                                    \
            const float4* wih4 = (const float4*)(W_ih + (ROW) * NEMB);       \
            _Pragma("unroll")                                                \
            for (int e4 = 0; e4 < NEMB / 4; ++e4) {                          \
                float4 wv = wih4[e4];                                        \
                const float4* wm = ((const float4*)W_emb) + 4 * e4;          \
                PFX##0 += wv.x*wm[0].x + wv.y*wm[1].x + wv.z*wm[2].x + wv.w*wm[3].x; \
                PFX##1 += wv.x*wm[0].y + wv.y*wm[1].y + wv.z*wm[2].y + wv.w*wm[3].y; \
                PFX##2 += wv.x*wm[0].z + wv.y*wm[1].z + wv.z*wm[2].z + wv.w*wm[3].z; \
                PFX##3 += wv.x*wm[0].w + wv.y*wm[1].w + wv.z*wm[2].w + wv.w*wm[3].w; \
                PFX##b += wv.x*b_emb[4*e4+0] + wv.y*b_emb[4*e4+1]            \
                        + wv.z*b_emb[4*e4+2] + wv.w*b_emb[4*e4+3];           \
            }                                                                \
        }
    FOLD(wcI, j)
    FOLD(wcF, NHID + j)
    FOLD(wcG, 2 * NHID + j)
    FOLD(wcO, 3 * NHID + j)
    #undef FOLD

    // ---- W_hh rows for the 4 gates of unit j, f16-packed (RNE): 32 half2 ----
    half2v wI[32], wF[32], wG[32], wO[32];
    {
        const float4* pI = (const float4*)(W_hh + (size_t)(j) * NHID);
        const float4* pF = (const float4*)(W_hh + (size_t)(NHID + j) * NHID);
        const float4* pG = (const float4*)(W_hh + (size_t)(2 * NHID + j) * NHID);
        const float4* pO = (const float4*)(W_hh + (size_t)(3 * NHID + j) * NHID);
        #pragma unroll
        for (int k = 0; k < 16; ++k) {
            float4 q;
            q = pI[k]; wI[2*k] = pack_rne(q.x, q.y); wI[2*k+1] = pack_rne(q.z, q.w);
            q = pF[k]; wF[2*k] = pack_rne(q.x, q.y); wF[2*k+1] = pack_rne(q.z, q.w);
            q = pG[k]; wG[2*k] = pack_rne(q.x, q.y); wG[2*k+1] = pack_rne(q.z, q.w);
            q = pO[k]; wO[2*k] = pack_rne(q.x, q.y); wO[2*k+1] = pack_rne(q.z, q.w);
        }
    }

    float* hs_out = hs_g + (size_t)m * (TT * NHID) + j;

    // ---- recurrence: 64 steps, NO barriers, exchange-free ----
    float c = 0.0f, h = 0.0f;
    #pragma unroll 1
    for (int t = 0; t < TT; ++t) {
        // x-term: 4 uniform readlanes (lane t holds x[t]), fp32
        const float xb0 = lanebcast(xl.x, t);
        const float xb1 = lanebcast(xl.y, t);
        const float xb2 = lanebcast(xl.z, t);
        const float xb3 = lanebcast(xl.w, t);
        float aI0 = wcIb + xb0 * wcI0 + xb2 * wcI2;
        float aI1 = xb1 * wcI1 + xb3 * wcI3;
        float aF0 = wcFb + xb0 * wcF0 + xb2 * wcF2;
        float aF1 = xb1 * wcF1 + xb3 * wcF3;
        float aG0 = wcGb + xb0 * wcG0 + xb2 * wcG2;
        float aG1 = xb1 * wcG1 + xb3 * wcG3;
        float aO0 = wcOb + xb0 * wcO0 + xb2 * wcO2;
        float aO1 = xb1 * wcO1 + xb3 * wcO3;

        // h split: h = h16 + e (residual), both RNE-packed as f16 pairs.
        // even lane 2k holds pair (unit 2k, unit 2k+1)
        const float h16f = (float)(__fp16)h;
        const float e    = h - h16f;
        const float hnb  = __shfl_xor(h, 1);
        const float enb  = __shfl_xor(e, 1);
        const int hpi = h22i(pack_rne(h, hnb));
        const int epi = h22i(pack_rne(e, enb));

        // ---- group 1: 32 batched broadcasts of h16 pairs, then 128 dot2 ----
        int hb[32];
        #pragma unroll
        for (int k = 0; k < 32; ++k)
            hb[k] = __builtin_amdgcn_readlane(hpi, 2 * k);
        #pragma unroll
        for (int k = 0; k < 32; k += 2) {
            const half2v h0 = i2h2(hb[k]);
            const half2v h1 = i2h2(hb[k + 1]);
            aI0 = __builtin_amdgcn_fdot2(h0, wI[k],     aI0, false);
            aI1 = __builtin_amdgcn_fdot2(h1, wI[k + 1], aI1, false);
            aF0 = __builtin_amdgcn_fdot2(h0, wF[k],     aF0, false);
            aF1 = __builtin_amdgcn_fdot2(h1, wF[k + 1], aF1, false);
            aG0 = __builtin_amdgcn_fdot2(h0, wG[k],     aG0, false);
            aG1 = __builtin_amdgcn_fdot2(h1, wG[k + 1], aG1, false);
            aO0 = __builtin_amdgcn_fdot2(h0, wO[k],     aO0, false);
            aO1 = __builtin_amdgcn_fdot2(h1, wO[k + 1], aO1, false);
        }

        // ---- group 2: 32 batched broadcasts of residual pairs, 128 dot2 ----
        int eb[32];
        #pragma unroll
        for (int k = 0; k < 32; ++k)
            eb[k] = __builtin_amdgcn_readlane(epi, 2 * k);
        #pragma unroll
        for (int k = 0; k < 32; k += 2) {
            const half2v e0 = i2h2(eb[k]);
            const half2v e1 = i2h2(eb[k + 1]);
            aI0 = __builtin_amdgcn_fdot2(e0, wI[k],     aI0, false);
            aI1 = __builtin_amdgcn_fdot2(e1, wI[k + 1], aI1, false);
            aF0 = __builtin_amdgcn_fdot2(e0, wF[k],     aF0, false);
            aF1 = __builtin_amdgcn_fdot2(e1, wF[k + 1], aF1, false);
            aG0 = __builtin_amdgcn_fdot2(e0, wG[k],     aG0, false);
            aG1 = __builtin_amdgcn_fdot2(e1, wG[k + 1], aG1, false);
            aO0 = __builtin_amdgcn_fdot2(e0, wO[k],     aO0, false);
            aO1 = __builtin_amdgcn_fdot2(e1, wO[k + 1], aO1, false);
        }

        const float ig = fast_sigmoid(aI0 + aI1);
        const float fg = fast_sigmoid(aF0 + aF1);
        const float gg = fast_tanh(aG0 + aG1);
        const float og = fast_sigmoid(aO0 + aO1);
        c = fg * c + ig * gg;
        h = og * fast_tanh(c);
        s_hs[t * (NHID + 1) + j] = h;   // LDS, no wait needed in-loop
        hs_out[t * NHID] = h;           // global, coalesced, fire-and-forget
    }
    __syncthreads();   // orders s_hs for the epilogue

    // ---- temporal attention pooling (softmax over t, i-independent) ----
    {
        const int t = j;   // lane = time index
        float r = 0.0f;
        #pragma unroll
        for (int k = 0; k < NHID; ++k)
            r += s_hs[t * (NHID + 1) + k] * s_war[k];
        float mx = r;
        #pragma unroll
        for (int off = 32; off >= 1; off >>= 1)
            mx = fmaxf(mx, __shfl_xor(mx, off));
        const float e = __expf(r - mx);
        float s = e;
        #pragma unroll
        for (int off = 32; off >= 1; off >>= 1)
            s += __shfl_xor(s, off);
        s_p[t] = __fdividef(e, s);
    }
    __syncthreads();

    {
        float acc = 0.0f;
        #pragma unroll
        for (int t = 0; t < TT; ++t)
            acc += s_p[t] * s_hs[t * (NHID + 1) + j];
        out[m * (2 * NHID) + j] = fast_tanh(acc);
    }
}

// ---------------------------------------------------------------------------
// Kernel 2: spatial inverse-distance aggregation (output cols 64..127)
// chsum[b,i,h] = sum_t sum_{j!=i} hs[b,j,t,h] / (dist(i,j,t)+eps)
// Grid: 160 blocks (b*40+i), 256 threads = (t-quarter q, h).
// ---------------------------------------------------------------------------
__global__ __launch_bounds__(256)
void k_spatial(const float* __restrict__ inputs,
               const float* __restrict__ hs_g,
               float* __restrict__ out)
{
    __shared__ float s_w[TT * NN];          // 2560 inverse-distance weights
    __shared__ float s_part[4 * NHID];

    const int bi  = blockIdx.x;
    const int b   = bi / NN;
    const int i   = bi - b * NN;
    const int tid = threadIdx.x;

    for (int idx = tid; idx < TT * NN; idx += 256) {
        const int t = idx / NN;
        const int j = idx - t * NN;
        const float* pi = inputs + ((b * NN + i) * TT + t) * NIN;
        const float* pj = inputs + ((b * NN + j) * TT + t) * NIN;
        const float dx = pi[0] - pj[0];
        const float dy = pi[1] - pj[1];
        const float d  = sqrtf(dx * dx + dy * dy);
        s_w[idx] = (j == i) ? 0.0f : __fdividef(1.0f, d + EPSW);
    }
    __syncthreads();

    const int h = tid & 63;
    const int q = tid >> 6;          // t-quarter

    const float* base = hs_g + (size_t)b * NN * TT * NHID + h;
    float a0 = 0.f, a1 = 0.f, a2 = 0.f, a3 = 0.f;
    for (int t = q * 16; t < q * 16 + 16; ++t) {
        const float* hp = base + t * NHID;
        const float* wp = s_w + t * NN;
        #pragma unroll
        for (int j = 0; j < NN; j += 4) {
            a0 += wp[j + 0] * hp[(size_t)(j + 0) * TT * NHID];
            a1 += wp[j + 1] * hp[(size_t)(j + 1) * TT * NHID];
            a2 += wp[j + 2] * hp[(size_t)(j + 2) * TT * NHID];
            a3 += wp[j + 3] * hp[(size_t)(j + 3) * TT * NHID];
        }
    }
    s_part[q * NHID + h] = (a0 + a1) + (a2 + a3);
    __syncthreads();

    if (tid < NHID) {
        const float s = s_part[tid] + s_part[NHID + tid] +
                        s_part[2 * NHID + tid] + s_part[3 * NHID + tid];
        out[bi * (2 * NHID) + NHID + tid] = fast_tanh(s);
    }
}

extern "C" void kernel_launch(void* const* d_in, const int* in_sizes, int n_in,
                              void* d_out, int out_size, void* d_ws, size_t ws_size,
                              hipStream_t stream) {
    const float* inputs = (const float*)d_in[0];
    // d_in[1..4]: rel_rec / rel_send / rel_rec_t / rel_send_t (one-hot, folded)
    const float* W_emb  = (const float*)d_in[5];
    const float* b_emb  = (const float*)d_in[6];
    const float* W_ih   = (const float*)d_in[7];
    const float* W_hh   = (const float*)d_in[8];
    const float* b_ih   = (const float*)d_in[9];
    const float* b_hh   = (const float*)d_in[10];
    const float* W_att  = (const float*)d_in[11];
    // d_in[12] = b_att: cancels in the softmax, unused.

    float* outp = (float*)d_out;
    float* hs_g = (float*)d_ws;   // 160*64*64 floats = 2.62 MB

    hipLaunchKernelGGL(k_lstm, dim3(BB * NN), dim3(64), 0, stream,
                       inputs, W_emb, b_emb, W_ih, W_hh, b_ih, b_hh, W_att,
                       outp, hs_g);
    hipLaunchKernelGGL(k_spatial, dim3(BB * NN), dim3(256), 0, stream,
                       inputs, hs_g, outp);
}